// Round 7
// baseline (220.921 us; speedup 1.0000x reference)
//
#include <hip/hip_runtime.h>
#include <hip/hip_bf16.h>

// IndRNN forward: proj = x @ W + b  (K=D=256), then
// h_t = relu(proj_t + h_{t-1} * clip(u,0,1)) over T.
// R7: SINGLE dispatch. Fused kernel stages fp32 x directly via
//     global_load_lds (x read exactly once; no conv pre-passes), converts
//     fp32->bf16 at fragment load with v_cvt_pk_bf16_f32, W-frags built
//     once per block from fp32 W (L2-hot). TC=32, GN=64, LDS 72 KB ->
//     2 blocks/CU. Waves 0-1 compute, 2-3 stage next chunk (issued at
//     phase-A start so compute hides the DMA drain), wave 0 scans.
//     All loops fixed-trip, plain stores, d_ws unused (R5 lessons).

typedef __bf16 bf16x8 __attribute__((ext_vector_type(8)));
typedef float f32x4 __attribute__((ext_vector_type(4)));

typedef const unsigned char __attribute__((address_space(1))) gc_t;
typedef unsigned char __attribute__((address_space(3))) lds_t;

__device__ __forceinline__ void gl_lds16(const void* g, void* l) {
    __builtin_amdgcn_global_load_lds((gc_t*)g, (lds_t*)l, 16, 0, 0);
}

union bfu { bf16x8 v; __hip_bfloat162 h[4]; };

// ------------------------------------------------------------ fused kernel
// Requires D == 256, U % 64 == 0, T % 32 == 0.
#define TC 32    // timesteps per chunk
#define GN 64    // units per block

__global__ __launch_bounds__(256, 2) void indrnn_fused(
    const float* __restrict__ x,     // fp32 [B*T, 256]
    const float* __restrict__ W,     // fp32 [256, U]
    const float* __restrict__ bias,  // [U]
    const float* __restrict__ h0,    // [B, U]
    const float* __restrict__ uvec,  // [U]
    float* __restrict__ out,         // [B, T, U]
    int B, int T, int U)
{
    // Xa rows are 1 KB (256 fp32); 16B-chunk c of row r lives at chunk c^(r&15)
    __shared__ __align__(16) float Xa[2][TC * 256];  // 2 x 32 KB fp32 chunks
    __shared__ __align__(16) float P[TC * GN];       // 8 KB fp32 proj

    const int tid  = threadIdx.x;
    const int lane = tid & 63;
    const int w    = tid >> 6;     // wave 0..3
    const int m    = lane & 15;
    const int quad = lane >> 4;    // 0..3
    const int b    = blockIdx.x;
    const int n0   = blockIdx.y * GN;
    const int tq   = (w & 1) * 16; // compute wave's 16-t stripe

    // ---- W fragments in registers (waves 0-1 only), built from fp32 W.
    // B-frag layout (verified R2-R6): n = n0+j*16+m, k = kt*32+quad*8+e.
    bfu bfr[4][8];
    if (w < 2) {
#pragma unroll
        for (int j = 0; j < 4; ++j)
#pragma unroll
            for (int kt = 0; kt < 8; ++kt) {
                const float* wp =
                    W + (long)(kt * 32 + quad * 8) * U + n0 + j * 16 + m;
                float f[8];
#pragma unroll
                for (int e = 0; e < 8; ++e) f[e] = wp[(long)e * U];
                bfr[j][kt].h[0] = __float22bfloat162_rn(make_float2(f[0], f[1]));
                bfr[j][kt].h[1] = __float22bfloat162_rn(make_float2(f[2], f[3]));
                bfr[j][kt].h[2] = __float22bfloat162_rn(make_float2(f[4], f[5]));
                bfr[j][kt].h[3] = __float22bfloat162_rn(make_float2(f[6], f[7]));
            }
    }

    float bb[4];
#pragma unroll
    for (int j = 0; j < 4; ++j) bb[j] = bias[n0 + j * 16 + m];

    float uc = 0.0f, h = 0.0f;
    if (tid < GN) {   // wave 0: lane owns unit n0+lane
        uc = fminf(fmaxf(uvec[n0 + tid], 0.0f), 1.0f);
        h  = h0[(long)b * U + n0 + tid];
    }

    const float* xg = x + (long)b * T * 256;

    // ---- prologue: all 4 waves stage chunk 0 (8 rows each, fixed trip).
    // lane fetches global 16B-chunk (lane ^ (r&15)); DMA puts it at LDS
    // chunk lane  =>  LDS chunk p holds global chunk p ^ (r&15).
#pragma unroll
    for (int i = 0; i < 8; ++i) {
        int r = w + i * 4;   // 0..31
        gl_lds16(xg + (long)r * 256 + ((lane ^ (r & 15)) << 2),
                 (char*)Xa[0] + r * 1024);
    }

    const int nch = T / TC;
    for (int c = 0; c < nch; ++c) {
        const f32x4* XF = (const f32x4*)Xa[c & 1];  // row r -> XF[r*64 + chunk]
        __syncthreads();   // B1: stage(c) in LDS; P free (prev scan done)

        if (w >= 2) {
            // ---- stagers: issue DMA for chunk c+1 (drained at B2,
            //      hidden by compute phase). Fixed trip, rows interleaved.
            if (c + 1 < nch) {
                const float* gn = xg + (long)(c + 1) * TC * 256;
                float* Xn = Xa[(c + 1) & 1];
#pragma unroll
                for (int i = 0; i < 16; ++i) {
                    int r = (w - 2) + i * 2;   // 0..31
                    gl_lds16(gn + (long)r * 256 + ((lane ^ (r & 15)) << 2),
                             (char*)Xn + r * 1024);
                }
            }
        } else {
            // ---- compute: 16t x 64u per wave; A from LDS fp32 (swizzled,
            //      cvt to bf16), B from registers.
            f32x4 acc[4];
#pragma unroll
            for (int j = 0; j < 4; ++j) acc[j] = (f32x4){0.f, 0.f, 0.f, 0.f};

#pragma unroll
            for (int kt = 0; kt < 8; ++kt) {
                const int c0 = kt * 8 + quad * 2;      // logical 16B chunk
                const int rowb = (tq + m) * 64;
                f32x4 p0 = XF[rowb + (c0 ^ m)];
                f32x4 p1 = XF[rowb + ((c0 + 1) ^ m)];
                bfu a;
                a.h[0] = __float22bfloat162_rn(make_float2(p0.x, p0.y));
                a.h[1] = __float22bfloat162_rn(make_float2(p0.z, p0.w));
                a.h[2] = __float22bfloat162_rn(make_float2(p1.x, p1.y));
                a.h[3] = __float22bfloat162_rn(make_float2(p1.z, p1.w));
#pragma unroll
                for (int j = 0; j < 4; ++j)
                    acc[j] = __builtin_amdgcn_mfma_f32_16x16x32_bf16(
                        a.v, bfr[j][kt].v, acc[j], 0, 0, 0);
            }

            // ---- proj (+bias) -> P, col XOR-swizzled by quad.
            // C/D layout: col = m (n), row = quad*4 + r (t). Verified R2-R6.
#pragma unroll
            for (int j = 0; j < 4; ++j)
#pragma unroll
                for (int r = 0; r < 4; ++r)
                    P[(tq + quad * 4 + r) * GN + ((j * 16 + m) ^ (quad << 4))] =
                        acc[j][r] + bb[j];
        }
        __syncthreads();   // B2: P visible; stage(c+1) DMA drained

        // ---- wave 0: scan chunk c (plain stores); others loop to B1
        if (w == 0) {
            float* og = out + ((long)b * T + (long)c * TC) * U + n0 + lane;
#pragma unroll
            for (int t = 0; t < TC; ++t) {
                float pv = P[t * GN + (lane ^ (((t >> 2) & 3) << 4))];
                h = fmaxf(fmaf(h, uc, pv), 0.0f);
                og[(long)t * U] = h;
            }
        }
    }
}

// ------------------------------------------------------------ fp32 fallback
#define BM 128
#define BN 128
#define BK 8

__global__ __launch_bounds__(256) void indrnn_gemm_bias(
    const float* __restrict__ A, const float* __restrict__ Bm,
    const float* __restrict__ bias, float* __restrict__ C,
    int M, int N, int K)
{
    __shared__ float As[BK][BM];
    __shared__ float Bs[BK][BN];
    const int tid = threadIdx.x;
    const int row0 = blockIdx.x * BM, col0 = blockIdx.y * BN;
    const int tx = tid & 15, ty = tid >> 4;
    float acc[8][8];
#pragma unroll
    for (int i = 0; i < 8; ++i)
#pragma unroll
        for (int j = 0; j < 8; ++j) acc[i][j] = 0.0f;
    const int am = tid >> 1, ak = (tid & 1) * 4;
    const int bk = tid >> 5, bn = (tid & 31) * 4;
    const float* Aptr = A + (long)(row0 + am) * K + ak;
    const float* Bptr = Bm + (long)bk * N + col0 + bn;
    for (int kt = 0; kt < K; kt += BK) {
        float4 av = *(const float4*)(Aptr + kt);
        float4 bv = *(const float4*)(Bptr + (long)kt * N);
        As[ak + 0][am] = av.x; As[ak + 1][am] = av.y;
        As[ak + 2][am] = av.z; As[ak + 3][am] = av.w;
        *(float4*)&Bs[bk][bn] = bv;
        __syncthreads();
#pragma unroll
        for (int k = 0; k < BK; ++k) {
            float4 a0 = *(const float4*)&As[k][ty * 4];
            float4 a1 = *(const float4*)&As[k][64 + ty * 4];
            float4 b0 = *(const float4*)&Bs[k][tx * 4];
            float4 b1 = *(const float4*)&Bs[k][64 + tx * 4];
            float a[8] = {a0.x, a0.y, a0.z, a0.w, a1.x, a1.y, a1.z, a1.w};
            float bb2[8] = {b0.x, b0.y, b0.z, b0.w, b1.x, b1.y, b1.z, b1.w};
#pragma unroll
            for (int i = 0; i < 8; ++i)
#pragma unroll
                for (int j = 0; j < 8; ++j)
                    acc[i][j] = fmaf(a[i], bb2[j], acc[i][j]);
        }
        __syncthreads();
    }
    float bb[8];
#pragma unroll
    for (int j = 0; j < 4; ++j) {
        bb[j] = bias[col0 + tx * 4 + j];
        bb[j + 4] = bias[col0 + 64 + tx * 4 + j];
    }
#pragma unroll
    for (int i = 0; i < 8; ++i) {
        const int r = (i < 4) ? (ty * 4 + i) : (64 + ty * 4 + (i - 4));
        float* crow = C + (long)(row0 + r) * N + col0;
        float4 v0 = {acc[i][0] + bb[0], acc[i][1] + bb[1], acc[i][2] + bb[2], acc[i][3] + bb[3]};
        float4 v1 = {acc[i][4] + bb[4], acc[i][5] + bb[5], acc[i][6] + bb[6], acc[i][7] + bb[7]};
        *(float4*)(crow + tx * 4) = v0;
        *(float4*)(crow + 64 + tx * 4) = v1;
    }
}

#define SCAN_UNROLL 32

__global__ __launch_bounds__(256) void indrnn_scan(
    float* __restrict__ out, const float* __restrict__ h0,
    const float* __restrict__ u, int B, int T, int U)
{
    const int idx = blockIdx.x * blockDim.x + threadIdx.x;
    if (idx >= B * U) return;
    const int b = idx / U;
    const int un = idx - b * U;
    const float uc = fminf(fmaxf(u[un], 0.0f), 1.0f);
    float h = h0[(long)b * U + un];
    float* p = out + (long)b * T * U + un;
    for (int t = 0; t < T; t += SCAN_UNROLL) {
        float pv[SCAN_UNROLL];
#pragma unroll
        for (int i = 0; i < SCAN_UNROLL; ++i)
            pv[i] = p[(long)(t + i) * U];
#pragma unroll
        for (int i = 0; i < SCAN_UNROLL; ++i) {
            h = fmaxf(fmaf(h, uc, pv[i]), 0.0f);
            pv[i] = h;
        }
#pragma unroll
        for (int i = 0; i < SCAN_UNROLL; ++i)
            p[(long)(t + i) * U] = pv[i];
    }
}

// ------------------------------------------------------------ launch
extern "C" void kernel_launch(void* const* d_in, const int* in_sizes, int n_in,
                              void* d_out, int out_size, void* d_ws, size_t ws_size,
                              hipStream_t stream) {
    const float* x  = (const float*)d_in[0]; // [B,T,D]
    const float* h0 = (const float*)d_in[1]; // [B,U]
    const float* W  = (const float*)d_in[2]; // [D,U]
    const float* u  = (const float*)d_in[3]; // [U]
    const float* b  = (const float*)d_in[4]; // [U]
    float* out = (float*)d_out;              // [B,T,U]

    const int U = in_sizes[3];
    const int B = in_sizes[1] / U;
    const int D = in_sizes[2] / U;
    const int T = in_sizes[0] / (B * D);
    const int M = B * T;

    const bool fused_ok = (D == 256) && (U % GN == 0) && (T % TC == 0);

    if (fused_ok) {
        dim3 g(B, U / GN);
        indrnn_fused<<<g, 256, 0, stream>>>(x, W, b, h0, u, out, B, T, U);
    } else {
        dim3 ggrid(M / BM, U / BN);
        indrnn_gemm_bias<<<ggrid, 256, 0, stream>>>(x, W, b, out, M, U, D);
        const int nthreads = B * U;
        indrnn_scan<<<(nthreads + 255) / 256, 256, 0, stream>>>(out, h0, u, B, T, U);
    }
}

// Round 8
// 134.169 us; speedup vs baseline: 1.6466x; 1.6466x over previous
//
#include <hip/hip_runtime.h>

// IndRNN forward: proj = x @ W + b  (K=D=256), then
// h_t = relu(proj_t + h_{t-1} * clip(u,0,1)) over T.
// R8: abandon intra-kernel chunk pipelining (R3/R4/R6/R7: 39-147 us, fragile).
//     Three dispatches, each at FULL wave-parallelism:
//       1) conv_wt: W -> Wt bf16 (512 KB)
//       2) gemm_proj: 1024 blocks, 128x128 tile, stages fp32 x via
//          global_load_lds (granule-XOR swizzle for the 128B fp32 row,
//          <=2-way read conflicts), cvt->bf16 at fragment load, proj bf16 -> ws
//       3) scan_bf: 512 waves, lane per (b,u), 32-deep prefetch, no barriers.

__device__ __forceinline__ unsigned short f2bf(float f) {
    unsigned int u = __float_as_uint(f);
    unsigned int r = (u + 0x7FFF + ((u >> 16) & 1)) >> 16;  // RNE
    return (unsigned short)r;
}

typedef __bf16 bf16x8 __attribute__((ext_vector_type(8)));
typedef float f32x4 __attribute__((ext_vector_type(4)));

typedef const unsigned char __attribute__((address_space(1))) gc_t;
typedef unsigned char __attribute__((address_space(3))) lds_t;

__device__ __forceinline__ void gl_lds16(const void* g, void* l) {
    __builtin_amdgcn_global_load_lds((gc_t*)g, (lds_t*)l, 16, 0, 0);
}

union bfu { bf16x8 v; unsigned u32[4]; };

__device__ __forceinline__ unsigned pk2(float lo, float hi) {
    return (unsigned)f2bf(lo) | ((unsigned)f2bf(hi) << 16);
}

// ------------------------------------------------------------ conv_wt
// W [K,N] fp32 -> Wt [N,K] bf16 (transpose), 256 KB out.
__global__ __launch_bounds__(256) void conv_wt(
    const float* __restrict__ W, unsigned short* __restrict__ Wt, int K, int N)
{
    int idx = blockIdx.x * blockDim.x + threadIdx.x;
    int kq = K >> 2;
    if (idx >= N * kq) return;
    int n = idx / kq;
    int k4 = (idx - n * kq) * 4;
    ushort4 o;
    o.x = f2bf(W[(long)(k4 + 0) * N + n]);
    o.y = f2bf(W[(long)(k4 + 1) * N + n]);
    o.z = f2bf(W[(long)(k4 + 2) * N + n]);
    o.w = f2bf(W[(long)(k4 + 3) * N + n]);
    *(ushort4*)(Wt + (long)n * K + k4) = o;
}

// ------------------------------------------------------------ GEMM -> proj bf16
// proj[M,N](bf16) = x[M,K](fp32, cvt) @ Wt[N,K]^T(bf16) + bias.
// Requires K == 256, M % 128 == 0, N % 128 == 0.
#define QM 128
#define QN 128
#define QK 32

__global__ __launch_bounds__(256) void gemm_proj(
    const float* __restrict__ x,            // [M, 256]
    const unsigned short* __restrict__ Wt,  // bf16 [N, 256]
    const float* __restrict__ bias,         // [N]
    unsigned short* __restrict__ proj,      // bf16 [M, N]
    int M, int N, int K)
{
    __shared__ __align__(16) float  As[QM * QK];   // 16 KB, granule-swizzled
    __shared__ __align__(16) __bf16 Bs[QN * QK];   // 8 KB, R1-proven swizzle

    const int tid  = threadIdx.x;
    const int lane = tid & 63;
    const int w    = tid >> 6;
    const int m    = lane & 15;
    const int quad = lane >> 4;
    const int col0 = blockIdx.x * QN;   // n-block fast -> x-tile L2 reuse
    const int row0 = blockIdx.y * QM;

    const int rowA_base = (w >> 1) * 64;
    const int colB_base = (w & 1) * 64;

    // A staging lane roles: call covers 8 rows x 8 granules (16B each).
    const int ar = lane >> 3;            // row within 8-row call
    const int ap = lane & 7;             // LDS granule slot within row
    // global granule fetched for LDS slot ap of row r:
    //   gp = ap ^ ((r&3)<<1) ^ ((r>>2)&1)
    // B staging (R1 verbatim): call covers 16 rows x 4 granules.
    const int sr = lane >> 2;
    const int sg = ((lane & 3) - ((sr >> 1) & 3)) & 3;
    const int bslot = (((m >> 1) & 3) + quad) & 3;   // B frag read slot (R1)

    // A frag read slots: logical granules 2*quad, 2*quad+1 of row i*16+m,
    // LDS slots = G ^ f(m), f = ((m&3)<<1) ^ ((m>>2)&1)
    const int af_ = ((m & 3) << 1) ^ ((m >> 2) & 1);
    const int ag0 = (2 * quad) ^ af_;
    const int ag1 = (2 * quad + 1) ^ af_;

    f32x4 acc[4][4];
#pragma unroll
    for (int i = 0; i < 4; ++i)
#pragma unroll
        for (int j = 0; j < 4; ++j) acc[i][j] = (f32x4){0.f, 0.f, 0.f, 0.f};

    for (int kt = 0; kt < K; kt += QK) {
        // ---- stage A: 128 rows x 128B fp32, 16 calls (4/wave)
#pragma unroll
        for (int c = 0; c < 4; ++c) {
            int rb = w * 32 + c * 8;          // call base row
            int r  = rb + ar;
            int gp = ap ^ ((r & 3) << 1) ^ ((r >> 2) & 1);
            gl_lds16(x + (long)(row0 + r) * 256 + kt + gp * 4,
                     (char*)As + rb * 128);
        }
        // ---- stage B: 128 rows x 64B bf16, 8 calls (2/wave), R1 pattern
#pragma unroll
        for (int c = 0; c < 2; ++c) {
            int rt = w * 32 + c * 16;
            gl_lds16(Wt + (long)(col0 + rt + sr) * 256 + kt + sg * 8,
                     (char*)Bs + rt * 64);
        }
        __syncthreads();

        bfu af[4];
        bf16x8 bf[4];
#pragma unroll
        for (int i = 0; i < 4; ++i) {
            const float* ab = As + (rowA_base + i * 16 + m) * 32;
            f32x4 p0 = *(const f32x4*)(ab + ag0 * 4);
            f32x4 p1 = *(const f32x4*)(ab + ag1 * 4);
            af[i].u32[0] = pk2(p0.x, p0.y);
            af[i].u32[1] = pk2(p0.z, p0.w);
            af[i].u32[2] = pk2(p1.x, p1.y);
            af[i].u32[3] = pk2(p1.z, p1.w);
            bf[i] = *(const bf16x8*)(Bs + (colB_base + i * 16 + m) * 32 +
                                     bslot * 8);
        }
#pragma unroll
        for (int i = 0; i < 4; ++i)
#pragma unroll
            for (int j = 0; j < 4; ++j)
                acc[i][j] = __builtin_amdgcn_mfma_f32_16x16x32_bf16(
                    af[i].v, bf[j], acc[i][j], 0, 0, 0);
        __syncthreads();
    }

    // ---- epilogue: +bias, cvt bf16, scalar stores (R1-proven orientation:
    // row(t) = row0+rowA_base+i*16+quad*4+r, col(n) = col0+colB_base+j*16+m)
    float bb[4];
#pragma unroll
    for (int j = 0; j < 4; ++j) bb[j] = bias[col0 + colB_base + j * 16 + m];

#pragma unroll
    for (int i = 0; i < 4; ++i)
#pragma unroll
        for (int r = 0; r < 4; ++r) {
            int row = row0 + rowA_base + i * 16 + quad * 4 + r;
            unsigned short* prow =
                proj + (long)row * N + col0 + colB_base + m;
#pragma unroll
            for (int j = 0; j < 4; ++j)
                prow[j * 16] = f2bf(acc[i][j][r] + bb[j]);
        }
}

// ------------------------------------------------------------ scan (bf16 proj)
#define SU 32

__global__ __launch_bounds__(64) void scan_bf(
    const unsigned short* __restrict__ proj,  // bf16 [B,T,U]
    const float* __restrict__ h0, const float* __restrict__ u,
    float* __restrict__ out, int B, int T, int U)
{
    const int idx = blockIdx.x * 64 + threadIdx.x;
    const int b = idx / U;
    const int un = idx - b * U;

    const float uc = fminf(fmaxf(u[un], 0.0f), 1.0f);
    float h = h0[(long)b * U + un];
    const unsigned short* p = proj + (long)b * T * U + un;
    float* o = out + (long)b * T * U + un;

    for (int t = 0; t < T; t += SU) {
        float pv[SU];
#pragma unroll
        for (int i = 0; i < SU; ++i) {
            unsigned bits = (unsigned)p[(long)(t + i) * U] << 16;
            pv[i] = __uint_as_float(bits);
        }
#pragma unroll
        for (int i = 0; i < SU; ++i) {
            h = fmaxf(fmaf(h, uc, pv[i]), 0.0f);
            pv[i] = h;
        }
#pragma unroll
        for (int i = 0; i < SU; ++i)
            o[(long)(t + i) * U] = pv[i];
    }
}

// ------------------------------------------------------------ fp32 fallback
#define BM 128
#define BN 128
#define BK 8

__global__ __launch_bounds__(256) void indrnn_gemm_bias(
    const float* __restrict__ A, const float* __restrict__ Bm,
    const float* __restrict__ bias, float* __restrict__ C,
    int M, int N, int K)
{
    __shared__ float As[BK][BM];
    __shared__ float Bs[BK][BN];
    const int tid = threadIdx.x;
    const int row0 = blockIdx.x * BM, col0 = blockIdx.y * BN;
    const int tx = tid & 15, ty = tid >> 4;
    float acc[8][8];
#pragma unroll
    for (int i = 0; i < 8; ++i)
#pragma unroll
        for (int j = 0; j < 8; ++j) acc[i][j] = 0.0f;
    const int am = tid >> 1, ak = (tid & 1) * 4;
    const int bk = tid >> 5, bn = (tid & 31) * 4;
    const float* Aptr = A + (long)(row0 + am) * K + ak;
    const float* Bptr = Bm + (long)bk * N + col0 + bn;
    for (int kt = 0; kt < K; kt += BK) {
        float4 av = *(const float4*)(Aptr + kt);
        float4 bv = *(const float4*)(Bptr + (long)kt * N);
        As[ak + 0][am] = av.x; As[ak + 1][am] = av.y;
        As[ak + 2][am] = av.z; As[ak + 3][am] = av.w;
        *(float4*)&Bs[bk][bn] = bv;
        __syncthreads();
#pragma unroll
        for (int k = 0; k < BK; ++k) {
            float4 a0 = *(const float4*)&As[k][ty * 4];
            float4 a1 = *(const float4*)&As[k][64 + ty * 4];
            float4 b0 = *(const float4*)&Bs[k][tx * 4];
            float4 b1 = *(const float4*)&Bs[k][64 + tx * 4];
            float a[8] = {a0.x, a0.y, a0.z, a0.w, a1.x, a1.y, a1.z, a1.w};
            float bb2[8] = {b0.x, b0.y, b0.z, b0.w, b1.x, b1.y, b1.z, b1.w};
#pragma unroll
            for (int i = 0; i < 8; ++i)
#pragma unroll
                for (int j = 0; j < 8; ++j)
                    acc[i][j] = fmaf(a[i], bb2[j], acc[i][j]);
        }
        __syncthreads();
    }
    float bb[8];
#pragma unroll
    for (int j = 0; j < 4; ++j) {
        bb[j] = bias[col0 + tx * 4 + j];
        bb[j + 4] = bias[col0 + 64 + tx * 4 + j];
    }
#pragma unroll
    for (int i = 0; i < 8; ++i) {
        const int r = (i < 4) ? (ty * 4 + i) : (64 + ty * 4 + (i - 4));
        float* crow = C + (long)(row0 + r) * N + col0;
        float4 v0 = {acc[i][0] + bb[0], acc[i][1] + bb[1], acc[i][2] + bb[2], acc[i][3] + bb[3]};
        float4 v1 = {acc[i][4] + bb[4], acc[i][5] + bb[5], acc[i][6] + bb[6], acc[i][7] + bb[7]};
        *(float4*)(crow + tx * 4) = v0;
        *(float4*)(crow + 64 + tx * 4) = v1;
    }
}

__global__ __launch_bounds__(256) void indrnn_scan(
    float* __restrict__ out, const float* __restrict__ h0,
    const float* __restrict__ u, int B, int T, int U)
{
    const int idx = blockIdx.x * blockDim.x + threadIdx.x;
    if (idx >= B * U) return;
    const int b = idx / U;
    const int un = idx - b * U;
    const float uc = fminf(fmaxf(u[un], 0.0f), 1.0f);
    float h = h0[(long)b * U + un];
    float* p = out + (long)b * T * U + un;
    for (int t = 0; t < T; t += SU) {
        float pv[SU];
#pragma unroll
        for (int i = 0; i < SU; ++i)
            pv[i] = p[(long)(t + i) * U];
#pragma unroll
        for (int i = 0; i < SU; ++i) {
            h = fmaxf(fmaf(h, uc, pv[i]), 0.0f);
            pv[i] = h;
        }
#pragma unroll
        for (int i = 0; i < SU; ++i)
            p[(long)(t + i) * U] = pv[i];
    }
}

// ------------------------------------------------------------ launch
extern "C" void kernel_launch(void* const* d_in, const int* in_sizes, int n_in,
                              void* d_out, int out_size, void* d_ws, size_t ws_size,
                              hipStream_t stream) {
    const float* x  = (const float*)d_in[0]; // [B,T,D]
    const float* h0 = (const float*)d_in[1]; // [B,U]
    const float* W  = (const float*)d_in[2]; // [D,U]
    const float* u  = (const float*)d_in[3]; // [U]
    const float* b  = (const float*)d_in[4]; // [U]
    float* out = (float*)d_out;              // [B,T,U]

    const int U = in_sizes[3];
    const int B = in_sizes[1] / U;
    const int D = in_sizes[2] / U;
    const int T = in_sizes[0] / (B * D);
    const int M = B * T;

    const size_t proj_bytes = (size_t)M * U * sizeof(unsigned short);
    const size_t wt_bytes   = (size_t)U * D * sizeof(unsigned short);
    const bool ok = (D == 256) && (M % QM == 0) && (U % QN == 0) &&
                    (T % SU == 0) && ((B * U) % 64 == 0) &&
                    (ws_size >= proj_bytes + wt_bytes);

    if (ok) {
        unsigned short* proj = (unsigned short*)d_ws;
        unsigned short* wt   = (unsigned short*)((char*)d_ws + proj_bytes);

        const int nwt = U * (D / 4);
        conv_wt<<<(nwt + 255) / 256, 256, 0, stream>>>(W, wt, D, U);

        dim3 gg(U / QN, M / QM);   // n-block fast for x-tile L2 reuse
        gemm_proj<<<gg, 256, 0, stream>>>(x, wt, b, proj, M, U, D);

        scan_bf<<<(B * U) / 64, 64, 0, stream>>>(proj, h0, u, out, B, T, U);
    } else {
        dim3 ggrid(M / BM, U / BN);
        indrnn_gemm_bias<<<ggrid, 256, 0, stream>>>(x, W, b, out, M, U, D);
        const int nthreads = B * U;
        indrnn_scan<<<(nthreads + 255) / 256, 256, 0, stream>>>(out, h0, u, B, T, U);
    }
}